// Round 1
// 900.781 us; speedup vs baseline: 1.0267x; 1.0267x over previous
//
#include <hip/hip_runtime.h>

#define E_EDGES 320000
#define N_NODES 10000
#define DEG_CAP 128

typedef __attribute__((ext_vector_type(8))) short bf16x8;
typedef __attribute__((ext_vector_type(4))) float f32x4;

__device__ __forceinline__ unsigned short f2bf(float x) {
  union { float f; unsigned u; } v; v.f = x;
  unsigned r = v.u + 0x7FFFu + ((v.u >> 16) & 1u);
  return (unsigned short)(r >> 16);
}
__device__ __forceinline__ float bf2f(unsigned short s) {
  union { unsigned u; float f; } v; v.u = ((unsigned)s) << 16;
  return v.f;
}

// ---------------- prep: W1 -> W1at/W1bt bf16 [n][k], W2 -> W2t bf16 [n][k] ----
__global__ __launch_bounds__(256) void prep_kernel(
    const float* __restrict__ W1, const float* __restrict__ W2,
    unsigned short* __restrict__ W1at, unsigned short* __restrict__ W1bt,
    unsigned short* __restrict__ W2t) {
  int tid = blockIdx.x * 256 + threadIdx.x;
  if (tid < 512 * 256) {
    int n = tid >> 8, k = tid & 255;          // W1at/W1bt: [512 n][256 k]
    W1at[tid] = f2bf(W1[k * 512 + n]);
    W1bt[tid] = f2bf(W1[(k + 256) * 512 + n]);
  } else {
    int t = tid - 512 * 256;
    if (t < 256 * 512) {
      int n = t >> 9, k = t & 511;            // W2t: [256 n][512 k]
      W2t[t] = f2bf(W2[k * 256 + n]);
    }
  }
}

// ---------------- U = x_in @ W1[0:256,:] + b1   -> bf16 [node][512] ----------
// Swapped operands: D[col][node]; lane holds 4 contiguous cols -> ushort4 store.
__global__ __launch_bounds__(256) void u_kernel(
    const float* __restrict__ x_in, const unsigned short* __restrict__ W1at,
    const float* __restrict__ b1, unsigned short* __restrict__ U) {
  __shared__ unsigned short x_lds[64 * 264];
  int tid = threadIdx.x;
  int m0g = blockIdx.x * 64;
  for (int it = 0; it < 16; ++it) {
    int i = it * 256 + tid;
    int r = i >> 6, c = i & 63;
    int node = m0g + r;
    float4 v = make_float4(0.f, 0.f, 0.f, 0.f);
    if (node < N_NODES) v = *(const float4*)(x_in + node * 256 + c * 4);
    ushort4 s4;
    s4.x = f2bf(v.x); s4.y = f2bf(v.y); s4.z = f2bf(v.z); s4.w = f2bf(v.w);
    *(ushort4*)(x_lds + r * 264 + c * 4) = s4;
  }
  __syncthreads();
  int w = tid >> 6, l = tid & 63, quad = l >> 4, lid = l & 15;
  int cb = blockIdx.y * 128 + w * 32;
  f32x4 acc[2][4];
#pragma unroll
  for (int a = 0; a < 2; ++a)
#pragma unroll
    for (int b = 0; b < 4; ++b) acc[a][b] = (f32x4){0.f, 0.f, 0.f, 0.f};
  bf16x8 ac[2], an[2];
#pragma unroll
  for (int mf2 = 0; mf2 < 2; ++mf2)
    ac[mf2] = *(const bf16x8*)(W1at + (size_t)(cb + mf2 * 16 + lid) * 256 + quad * 8);
#pragma unroll
  for (int kk = 0; kk < 8; ++kk) {
    if (kk < 7) {
#pragma unroll
      for (int mf2 = 0; mf2 < 2; ++mf2)
        an[mf2] = *(const bf16x8*)(W1at + (size_t)(cb + mf2 * 16 + lid) * 256 + (kk + 1) * 32 + quad * 8);
    }
    bf16x8 xf[4];
#pragma unroll
    for (int nf2 = 0; nf2 < 4; ++nf2)
      xf[nf2] = *(const bf16x8*)(x_lds + (nf2 * 16 + lid) * 264 + kk * 32 + quad * 8);
#pragma unroll
    for (int mf2 = 0; mf2 < 2; ++mf2)
#pragma unroll
      for (int nf2 = 0; nf2 < 4; ++nf2)
        acc[mf2][nf2] = __builtin_amdgcn_mfma_f32_16x16x32_bf16(ac[mf2], xf[nf2], acc[mf2][nf2], 0, 0, 0);
#pragma unroll
    for (int mf2 = 0; mf2 < 2; ++mf2) ac[mf2] = an[mf2];
  }
#pragma unroll
  for (int mf2 = 0; mf2 < 2; ++mf2) {
    int colb = cb + mf2 * 16 + quad * 4;
    float4 bv = *(const float4*)(b1 + colb);
#pragma unroll
    for (int nf2 = 0; nf2 < 4; ++nf2) {
      int node = m0g + nf2 * 16 + lid;
      if (node < N_NODES) {
        ushort4 s4;
        s4.x = f2bf(acc[mf2][nf2][0] + bv.x);
        s4.y = f2bf(acc[mf2][nf2][1] + bv.y);
        s4.z = f2bf(acc[mf2][nf2][2] + bv.z);
        s4.w = f2bf(acc[mf2][nf2][3] + bv.w);
        *(ushort4*)(U + (size_t)node * 512 + colb) = s4;
      }
    }
  }
}

// ---------------- CSR build: cnt histogram + padded perm in one pass ---------
__global__ __launch_bounds__(256) void csr_kernel(
    const int* __restrict__ EI, int* __restrict__ cnt, int* __restrict__ perm) {
  int e = blockIdx.x * 256 + threadIdx.x;
  if (e < E_EDGES) {
    int d = EI[e];
    d = min(max(d, 0), N_NODES - 1);
    int p = atomicAdd(cnt + d, 1);
    if (p < DEG_CAP) perm[d * DEG_CAP + p] = e;
  }
}

// ---------------- fused edge MLP, swapped-operand GEMMs ----------------------
// GEMM1b swapped: D[hidden][edge] -> lane holds 4 contiguous hidden per edge
//   => U gather is ushort4 (8B), h store is 8B LDS writes.
// GEMM2 swapped: D[outcol][edge] -> lane holds 4 contiguous outcols per edge
//   => message store is ushort4 (8B) coalesced streams.
#define EA_OFF 0            // 64 x 264 shorts = 33792 B
#define H_OFF  (64 * 264)   // 64 x 136 shorts = 17408 B
#define IDX_OFF (H_OFF + 64 * 136)  // 128 ints = 512 B
template <int USE_MSGS>
__global__ __launch_bounds__(256, 3) void main_kernel(
    const int* __restrict__ EI, const float* __restrict__ edge_attr,
    const unsigned short* __restrict__ W1bt, const unsigned short* __restrict__ W2t,
    const unsigned short* __restrict__ U, const float* __restrict__ b2,
    float* __restrict__ out, unsigned short* __restrict__ msgs) {
  __shared__ unsigned short lds[64 * 264 + 64 * 136 + 256];
  int* idx_lds = (int*)(lds + IDX_OFF);   // [0..63]=dst, [64..127]=src

  int tid = threadIdx.x;
  int e0 = blockIdx.x * 64;
  if (tid < 64) {
    int d = EI[e0 + tid];
    idx_lds[tid] = min(max(d, 0), N_NODES - 1);
  } else if (tid < 128) {
    int s = EI[E_EDGES + e0 + (tid - 64)];
    idx_lds[tid] = min(max(s, 0), N_NODES - 1);
  }
  for (int it = 0; it < 16; ++it) {
    int i = it * 256 + tid;
    int r = i >> 6, c = i & 63;
    float4 v = *(const float4*)(edge_attr + (size_t)(e0 + r) * 256 + c * 4);
    ushort4 s4;
    s4.x = f2bf(v.x); s4.y = f2bf(v.y); s4.z = f2bf(v.z); s4.w = f2bf(v.w);
    *(ushort4*)(lds + EA_OFF + r * 264 + c * 4) = s4;
  }
  __syncthreads();

  int w = tid >> 6, l = tid & 63, quad = l >> 4, lid = l & 15;

  f32x4 macc[4][4];   // [outcol-frag][edge-frag]
#pragma unroll
  for (int a = 0; a < 4; ++a)
#pragma unroll
    for (int b = 0; b < 4; ++b) macc[a][b] = (f32x4){0.f, 0.f, 0.f, 0.f};

  for (int nc = 0; nc < 4; ++nc) {
    int n0 = nc * 128;
    // ---- U prefetch: 8 x ushort4 loads (4 contiguous hidden per lane) ----
    ushort4 uq[2][4];
#pragma unroll
    for (int nf2 = 0; nf2 < 4; ++nf2) {
      int src = idx_lds[64 + nf2 * 16 + lid];
      const unsigned short* up = U + (size_t)src * 512 + n0 + w * 32 + quad * 4;
#pragma unroll
      for (int mf2 = 0; mf2 < 2; ++mf2)
        uq[mf2][nf2] = *(const ushort4*)(up + mf2 * 16);
    }
    // ---- GEMM1b (swapped): acc1[hidden-frag][edge-frag] ----
    f32x4 acc1[2][4];
#pragma unroll
    for (int a = 0; a < 2; ++a)
#pragma unroll
      for (int b = 0; b < 4; ++b) acc1[a][b] = (f32x4){0.f, 0.f, 0.f, 0.f};
    int arow = n0 + w * 32 + lid;
    bf16x8 a1c[2], a1n[2];
#pragma unroll
    for (int mf2 = 0; mf2 < 2; ++mf2)
      a1c[mf2] = *(const bf16x8*)(W1bt + (size_t)(arow + mf2 * 16) * 256 + quad * 8);
#pragma unroll
    for (int s = 0; s < 8; ++s) {
      if (s < 7) {
#pragma unroll
        for (int mf2 = 0; mf2 < 2; ++mf2)
          a1n[mf2] = *(const bf16x8*)(W1bt + (size_t)(arow + mf2 * 16) * 256 + (s + 1) * 32 + quad * 8);
      }
      int ka = s * 32 + quad * 8;
      bf16x8 ef[4];
#pragma unroll
      for (int nf2 = 0; nf2 < 4; ++nf2)
        ef[nf2] = *(const bf16x8*)(lds + EA_OFF + (nf2 * 16 + lid) * 264 + ka);
#pragma unroll
      for (int mf2 = 0; mf2 < 2; ++mf2)
#pragma unroll
        for (int nf2 = 0; nf2 < 4; ++nf2)
          acc1[mf2][nf2] = __builtin_amdgcn_mfma_f32_16x16x32_bf16(a1c[mf2], ef[nf2], acc1[mf2][nf2], 0, 0, 0);
#pragma unroll
      for (int mf2 = 0; mf2 < 2; ++mf2) a1c[mf2] = a1n[mf2];
    }
    // ---- epilogue1: h = relu(acc1 + U[src]); pack 4 bf16 -> 8B LDS write ----
    unsigned hp[2][4][2];
#pragma unroll
    for (int mf2 = 0; mf2 < 2; ++mf2)
#pragma unroll
      for (int nf2 = 0; nf2 < 4; ++nf2) {
        ushort4 u4 = uq[mf2][nf2];
        float h0 = acc1[mf2][nf2][0] + bf2f(u4.x);
        float h1 = acc1[mf2][nf2][1] + bf2f(u4.y);
        float h2 = acc1[mf2][nf2][2] + bf2f(u4.z);
        float h3 = acc1[mf2][nf2][3] + bf2f(u4.w);
        h0 = h0 > 0.f ? h0 : 0.f;
        h1 = h1 > 0.f ? h1 : 0.f;
        h2 = h2 > 0.f ? h2 : 0.f;
        h3 = h3 > 0.f ? h3 : 0.f;
        hp[mf2][nf2][0] = (unsigned)f2bf(h0) | ((unsigned)f2bf(h1) << 16);
        hp[mf2][nf2][1] = (unsigned)f2bf(h2) | ((unsigned)f2bf(h3) << 16);
      }
    __syncthreads();   // prev chunk's GEMM2 readers of h done
#pragma unroll
    for (int mf2 = 0; mf2 < 2; ++mf2)
#pragma unroll
      for (int nf2 = 0; nf2 < 4; ++nf2) {
        uint2 d;
        d.x = hp[mf2][nf2][0]; d.y = hp[mf2][nf2][1];
        *(uint2*)(lds + H_OFF + (nf2 * 16 + lid) * 136 + w * 32 + mf2 * 16 + quad * 4) = d;
      }
    __syncthreads();   // h visible
    // ---- GEMM2 (swapped): macc[outcol-frag][edge-frag] += W2t x h ----
    int orow = w * 64 + lid;
    bf16x8 c2[4], n2[4];
#pragma unroll
    for (int mf2 = 0; mf2 < 4; ++mf2)
      c2[mf2] = *(const bf16x8*)(W2t + (size_t)(orow + mf2 * 16) * 512 + n0 + quad * 8);
#pragma unroll
    for (int s2 = 0; s2 < 4; ++s2) {
      if (s2 < 3) {
#pragma unroll
        for (int mf2 = 0; mf2 < 4; ++mf2)
          n2[mf2] = *(const bf16x8*)(W2t + (size_t)(orow + mf2 * 16) * 512 + n0 + (s2 + 1) * 32 + quad * 8);
      }
      int kl = s2 * 32 + quad * 8;
      bf16x8 hf[4];
#pragma unroll
      for (int nf2 = 0; nf2 < 4; ++nf2)
        hf[nf2] = *(const bf16x8*)(lds + H_OFF + (nf2 * 16 + lid) * 136 + kl);
#pragma unroll
      for (int mf2 = 0; mf2 < 4; ++mf2)
#pragma unroll
        for (int nf2 = 0; nf2 < 4; ++nf2)
          macc[mf2][nf2] = __builtin_amdgcn_mfma_f32_16x16x32_bf16(c2[mf2], hf[nf2], macc[mf2][nf2], 0, 0, 0);
#pragma unroll
      for (int mf2 = 0; mf2 < 4; ++mf2) c2[mf2] = n2[mf2];
    }
  }
  // ---- epilogue2 ----
  if (USE_MSGS) {
    // stream messages (no b2; aggregation adds cnt*b2): 16 x 8B coalesced stores
#pragma unroll
    for (int nf2 = 0; nf2 < 4; ++nf2) {
      size_t ebase = (size_t)(e0 + nf2 * 16 + lid) * 256;
#pragma unroll
      for (int mf2 = 0; mf2 < 4; ++mf2) {
        int col = w * 64 + mf2 * 16 + quad * 4;
        ushort4 s4;
        s4.x = f2bf(macc[mf2][nf2][0]);
        s4.y = f2bf(macc[mf2][nf2][1]);
        s4.z = f2bf(macc[mf2][nf2][2]);
        s4.w = f2bf(macc[mf2][nf2][3]);
        *(ushort4*)(msgs + ebase + col) = s4;
      }
    }
  } else {
    // fallback: atomic scatter (4 contiguous cols per lane)
#pragma unroll
    for (int mf2 = 0; mf2 < 4; ++mf2) {
      int col = w * 64 + mf2 * 16 + quad * 4;
      float4 bv = *(const float4*)(b2 + col);
#pragma unroll
      for (int nf2 = 0; nf2 < 4; ++nf2) {
        int node = idx_lds[nf2 * 16 + lid];
        float* op = out + (size_t)node * 256 + col;
        atomicAdd(op + 0, macc[mf2][nf2][0] + bv.x);
        atomicAdd(op + 1, macc[mf2][nf2][1] + bv.y);
        atomicAdd(op + 2, macc[mf2][nf2][2] + bv.z);
        atomicAdd(op + 3, macc[mf2][nf2][3] + bv.w);
      }
    }
  }
}

// ---------------- aggregation: out[n] = sum(msgs[perm[n]]) + cnt[n]*b2 -------
__global__ __launch_bounds__(256) void agg_kernel(
    const unsigned short* __restrict__ msgs, const int* __restrict__ perm,
    const int* __restrict__ cnt, const float* __restrict__ b2,
    float* __restrict__ out) {
  int team = threadIdx.x >> 5, lane = threadIdx.x & 31;
  int node = blockIdx.x * 8 + team;
  int c = min(cnt[node], DEG_CAP);
  const int* pl = perm + node * DEG_CAP;
  float acc[8];
#pragma unroll
  for (int j = 0; j < 8; ++j) acc[j] = 0.f;
  int i = 0;
  for (; i + 2 <= c; i += 2) {
    int ea_ = pl[i], eb_ = pl[i + 1];
    bf16x8 va = *(const bf16x8*)(msgs + (size_t)ea_ * 256 + lane * 8);
    bf16x8 vb = *(const bf16x8*)(msgs + (size_t)eb_ * 256 + lane * 8);
#pragma unroll
    for (int j = 0; j < 8; ++j) acc[j] += bf2f((unsigned short)va[j]);
#pragma unroll
    for (int j = 0; j < 8; ++j) acc[j] += bf2f((unsigned short)vb[j]);
  }
  if (i < c) {
    int ea_ = pl[i];
    bf16x8 va = *(const bf16x8*)(msgs + (size_t)ea_ * 256 + lane * 8);
#pragma unroll
    for (int j = 0; j < 8; ++j) acc[j] += bf2f((unsigned short)va[j]);
  }
  float fc = (float)c;
  float4 b2a = *(const float4*)(b2 + lane * 8);
  float4 b2b = *(const float4*)(b2 + lane * 8 + 4);
  float4 o0, o1;
  o0.x = acc[0] + fc * b2a.x; o0.y = acc[1] + fc * b2a.y;
  o0.z = acc[2] + fc * b2a.z; o0.w = acc[3] + fc * b2a.w;
  o1.x = acc[4] + fc * b2b.x; o1.y = acc[5] + fc * b2b.y;
  o1.z = acc[6] + fc * b2b.z; o1.w = acc[7] + fc * b2b.w;
  *(float4*)(out + (size_t)node * 256 + lane * 8) = o0;
  *(float4*)(out + (size_t)node * 256 + lane * 8 + 4) = o1;
}

extern "C" void kernel_launch(void* const* d_in, const int* in_sizes, int n_in,
                              void* d_out, int out_size, void* d_ws, size_t ws_size,
                              hipStream_t stream) {
  const float* x_in      = (const float*)d_in[1];
  const int* EI          = (const int*)d_in[2];
  const float* edge_attr = (const float*)d_in[3];
  const float* W1        = (const float*)d_in[4];
  const float* b1        = (const float*)d_in[5];
  const float* W2        = (const float*)d_in[6];
  const float* b2        = (const float*)d_in[7];
  float* out = (float*)d_out;

  unsigned short* W1at = (unsigned short*)d_ws;
  unsigned short* W1bt = W1at + 512 * 256;
  unsigned short* W2t  = W1bt + 512 * 256;
  unsigned short* U    = W2t + 256 * 512;
  unsigned short* msgs = U + (size_t)N_NODES * 512;
  int* cnt  = (int*)(msgs + (size_t)E_EDGES * 256);
  int* perm = cnt + N_NODES;

  size_t need = ((size_t)(3 * 512 * 256) + (size_t)N_NODES * 512 + (size_t)E_EDGES * 256) * 2
              + ((size_t)N_NODES + (size_t)N_NODES * DEG_CAP) * 4;
  bool use_msgs = ws_size >= need;

  prep_kernel<<<1024, 256, 0, stream>>>(W1, W2, W1at, W1bt, W2t);
  u_kernel<<<dim3(157, 4), 256, 0, stream>>>(x_in, W1at, b1, U);
  if (use_msgs) {
    hipMemsetAsync(cnt, 0, (size_t)N_NODES * sizeof(int), stream);
    csr_kernel<<<(E_EDGES + 255) / 256, 256, 0, stream>>>(EI, cnt, perm);
    main_kernel<1><<<E_EDGES / 64, 256, 0, stream>>>(EI, edge_attr, W1bt, W2t, U, b2, out, msgs);
    agg_kernel<<<N_NODES / 8, 256, 0, stream>>>(msgs, perm, cnt, b2, out);
  } else {
    hipMemsetAsync(d_out, 0, (size_t)out_size * sizeof(float), stream);
    main_kernel<0><<<E_EDGES / 64, 256, 0, stream>>>(EI, edge_attr, W1bt, W2t, U, b2, out, msgs);
  }
}